// Round 6
// baseline (1111.345 us; speedup 1.0000x reference)
//
#include <hip/hip_runtime.h>
#include <cmath>

typedef unsigned short u16;
typedef unsigned int   u32;

using bf16x8 = __attribute__((ext_vector_type(8))) short;   // 8 bf16 in 4 VGPRs
using f32x4  = __attribute__((ext_vector_type(4))) float;

#define S_LEN 2048
#define NHEAD 32
#define HDIM  160
#define HID   5120   // NHEAD*HDIM
#define NQKV  15360  // HID + 2*HID

__device__ __forceinline__ f32x4 mfma16(bf16x8 a, bf16x8 b, f32x4 c) {
  return __builtin_amdgcn_mfma_f32_16x16x32_bf16(a, b, c, 0, 0, 0);
}

__device__ __forceinline__ u16 f2bf(float f) {          // RNE f32->bf16
  u32 u = __builtin_bit_cast(u32, f);
  u += 0x7FFFu + ((u >> 16) & 1u);
  return (u16)(u >> 16);
}
__device__ __forceinline__ float bf2f(u16 h) {
  u32 u = ((u32)h) << 16;
  return __builtin_bit_cast(float, u);
}

// async global->LDS, 16B per lane; LDS dest is wave-uniform base + lane*16
__device__ __forceinline__ void gload16(const void* g, void* l) {
  __builtin_amdgcn_global_load_lds((const __attribute__((address_space(1))) void*)g,
                                   (__attribute__((address_space(3))) void*)l, 16, 0, 0);
}

// ---------------- f32 -> bf16 convert (vectorized, 8 elems/thread) ------------
__global__ void cvt_bf16_kernel(const float* __restrict__ in, u16* __restrict__ out, int n8) {
  int i = blockIdx.x * 256 + threadIdx.x;
  if (i >= n8) return;
  const float4* p = (const float4*)in + (size_t)i * 2;
  float4 a = p[0], b = p[1];
  uint4 o;
  o.x = (u32)f2bf(a.x) | ((u32)f2bf(a.y) << 16);
  o.y = (u32)f2bf(a.z) | ((u32)f2bf(a.w) << 16);
  o.z = (u32)f2bf(b.x) | ((u32)f2bf(b.y) << 16);
  o.w = (u32)f2bf(b.z) | ((u32)f2bf(b.w) << 16);
  ((uint4*)out)[i] = o;
}

// ---------------- RoPE table: tab[s][j] = (cos, sin), j<80 -------------------
// eff=8192 -> mscale=1.0, ntk_alpha=3, base=10000*3^(160/158)
__global__ void rope_table_kernel(float2* __restrict__ tab) {
  int i = blockIdx.x * 256 + threadIdx.x;
  if (i >= S_LEN * 80) return;
  int s = i / 80, j = i % 80;
  double base = 10000.0 * pow(3.0, 160.0 / 158.0);
  double invf = pow(base, -((double)(2 * j)) / 160.0);
  double ang  = fmod((double)s * invf, 6.283185307179586476925287);
  tab[i] = make_float2((float)cos(ang), (float)sin(ang));
}

// ---------------- RoPE apply + head-major relayout ---------------------------
// src row layout: src[s*rowStride + h*headStride + d], d in [0,160)
// dst: dst[(h*2048 + s)*160 + d]   (bf16)
__global__ void rope_apply_kernel(const u16* __restrict__ src, const float2* __restrict__ tab,
                                  u16* __restrict__ dst, int headStride, int rowStride) {
  int i = blockIdx.x * 256 + threadIdx.x;           // over 2048*32*80 dword-pairs
  if (i >= S_LEN * NHEAD * 80) return;
  int dp = i % 80; int sh = i / 80; int h = sh % NHEAD; int s = sh / NHEAD;
  int d = 2 * dp;
  const u16* row = src + (size_t)s * rowStride + h * headStride;
  u32 q01 = *(const u32*)&row[d];
  u32 p01 = *(const u32*)&row[d < 80 ? d + 80 : d - 80];
  int j = (d < 80) ? d : d - 80;
  float2 cs0 = tab[s * 80 + j];
  float2 cs1 = tab[s * 80 + j + 1];
  float q0 = bf2f((u16)(q01 & 0xffff)), q1 = bf2f((u16)(q01 >> 16));
  float p0 = bf2f((u16)(p01 & 0xffff)), p1 = bf2f((u16)(p01 >> 16));
  float sgn = (d < 80) ? -1.f : 1.f;                // out = x*cos + rot_half(x)*sin
  float o0 = q0 * cs0.x + sgn * p0 * cs0.y;
  float o1 = q1 * cs1.x + sgn * p1 * cs1.y;
  u32 o = (u32)f2bf(o0) | ((u32)f2bf(o1) << 16);
  *(u32*)&dst[((size_t)h * S_LEN + s) * HDIM + d] = o;
}

// ---------------- V transpose: v-slice of fused QKV -> Vt[h][d][s] -----------
// src[(s)*rowStride + h*320 + 2dp] points at the V part (base pre-offset).
__global__ void vtrans_kernel(const u16* __restrict__ src, u16* __restrict__ Vt, int rowStride) {
  __shared__ u16 T[HDIM][72];                       // pad 64->72 (2-way max on reads)
  int h = blockIdx.y; int s0 = blockIdx.x * 64; int tid = threadIdx.x;
  for (int i = tid; i < 64 * 80; i += 256) {
    int s = i / 80, dp = i % 80;
    u32 v = *(const u32*)&src[(size_t)(s0 + s) * rowStride + h * 320 + 2 * dp];
    T[2 * dp][s]     = (u16)(v & 0xffff);
    T[2 * dp + 1][s] = (u16)(v >> 16);
  }
  __syncthreads();
  for (int i = tid; i < HDIM * 32; i += 256) {
    int d = i / 32, sp = i % 32;
    u32 v = (u32)T[d][2 * sp] | ((u32)T[d][2 * sp + 1] << 16);
    *(u32*)&Vt[((size_t)h * HDIM + d) * S_LEN + s0 + 2 * sp] = v;
  }
}

// ---------------- GEMM 256x256, 8-phase deep pipeline (T2+T3+T4+T5) -----------
// C[M,N] = A[M,K] @ B[N,K]^T, bf16 in, f32 acc. BK=64, 512 thr = 8 waves (2Mx4N),
// per-wave 128x64 out. LDS 128 KiB: As/Bs[2 dbuf][2 half][128 x 64] with
// st_16x32 swizzle on global source AND ds_read (rule #21; verified R5: 0 conflicts).
// K-step = 4 quadrant phases (q00,q01,q11,q10). Each phase: stage EXACTLY ONE
// 16 KB half-tile unit (2 gload_lds/thread) + ds_read only the new fragments
// (12/4/8/0) + barrier + 16 MFMA (setprio) + barrier. Staging schedule (derived
// so each overwrite lands after its region's last-reader barrier):
//   ph0 -> B1(kt+1), ph1 -> A1(kt+1), ph2 -> B0(kt+2), ph3 -> A0(kt+2)
// Single counted vmcnt(4) at ph3 (validates step kt+1's 4 units; 2 units stay
// in flight). Loads span >=4 phases; never drained mid-loop (T4).
// EPI 0: store bf16.  EPI 1: f32 out = acc + bias[n] + resid[m*N+n].
template<int EPI>
__global__ __launch_bounds__(512, 2) void gemm256(
    const u16* __restrict__ A, const u16* __restrict__ Bm, void* __restrict__ Cout,
    int M, int N, int K, const float* __restrict__ bias, const float* __restrict__ resid)
{
  __shared__ u16 As[2][2][8192];   // 64 KB  [dbuf][row-half][128*64 swizzled]
  __shared__ u16 Bs[2][2][8192];   // 64 KB
  int tid = threadIdx.x;
  int w = tid >> 6, l = tid & 63, l15 = l & 15, l4 = l >> 4;
  int wr = w >> 2, wc = w & 3;

  // XCD chunked swizzle (nwg % 8 == 0 for all launches here)
  int nbx = gridDim.x;
  int nwg = nbx * gridDim.y;
  int lin = blockIdx.y * nbx + blockIdx.x;
  int cpx = nwg >> 3;
  int swz = (lin & 7) * cpx + (lin >> 3);
  int bm = (swz / nbx) * 256, bn = (swz % nbx) * 256;

  // staging thread-constants: thread t covers row srow, 8 cols of a 32-col chunk;
  // dest is linear, logical source col gets the involution XOR (rule #21).
  int srow = tid >> 2;                                  // 0..127
  int scol = ((tid & 3) * 8) ^ ((srow & 8) ? 16 : 0);   // pre-swizzled source col
  const u16* gA0 = A  + (size_t)(bm +       srow) * K + scol;
  const u16* gA1 = A  + (size_t)(bm + 128 + srow) * K + scol;
  const u16* gB0 = Bm + (size_t)(bn +       srow) * K + scol;
  const u16* gB1 = Bm + (size_t)(bn + 128 + srow) * K + scol;
  int dstoff = w * 512;                                 // elems (wave-uniform)

  f32x4 acc[8][4];
#pragma unroll
  for (int i = 0; i < 8; i++)
#pragma unroll
    for (int j = 0; j < 4; j++) acc[i][j] = f32x4{0.f, 0.f, 0.f, 0.f};

  int cA = (l4 * 8) ^ ((l15 & 8) ? 16 : 0);             // read-side swizzle (const)
  int bcol = (wc & 1) * 64;
  const int NT = K >> 6;                                // 80 for K=5120

  // one half-tile unit = 16 KB = 2 gload_lds per thread
  auto ST_A0 = [&](int kt) { int k0 = kt << 6, p = kt & 1;
    gload16(gA0 + k0, &As[p][0][dstoff]); gload16(gA0 + k0 + 32, &As[p][0][4096 + dstoff]); };
  auto ST_A1 = [&](int kt) { int k0 = kt << 6, p = kt & 1;
    gload16(gA1 + k0, &As[p][1][dstoff]); gload16(gA1 + k0 + 32, &As[p][1][4096 + dstoff]); };
  auto ST_B0 = [&](int kt) { int k0 = kt << 6, p = kt & 1;
    gload16(gB0 + k0, &Bs[p][0][dstoff]); gload16(gB0 + k0 + 32, &Bs[p][0][4096 + dstoff]); };
  auto ST_B1 = [&](int kt) { int k0 = kt << 6, p = kt & 1;
    gload16(gB1 + k0, &Bs[p][1][dstoff]); gload16(gB1 + k0 + 32, &Bs[p][1][4096 + dstoff]); };

  // prologue: steady-state issue order entering kt=0.ph0
  ST_B0(0); ST_A0(0); ST_B1(0); ST_A1(0); ST_B0(1); ST_A0(1);
  asm volatile("s_waitcnt vmcnt(4)" ::: "memory");      // step-0 units landed
  __builtin_amdgcn_s_barrier();

  bf16x8 aF0[4][2], aF1[4][2], bF0[2][2], bF1[2][2];

  for (int kt = 0; kt < NT; ++kt) {
    int p = kt & 1;
    const u16* Ah = &As[p][wr][0];
    const u16* Bh = &Bs[p][wc >> 1][0];

    // ---- ph0: quadrant (qm0,qn0). reads: aF0 (8) + bF0 (4)
    if (kt + 1 < NT) ST_B1(kt + 1);
#pragma unroll
    for (int mi = 0; mi < 4; ++mi)
#pragma unroll
      for (int kk = 0; kk < 2; ++kk)
        aF0[mi][kk] = *(const bf16x8*)&Ah[kk * 4096 + (mi * 16 + l15) * 32 + cA];
#pragma unroll
    for (int ni = 0; ni < 2; ++ni)
#pragma unroll
      for (int kk = 0; kk < 2; ++kk)
        bF0[ni][kk] = *(const bf16x8*)&Bh[kk * 4096 + (bcol + ni * 16 + l15) * 32 + cA];
    __builtin_amdgcn_s_barrier();
    __builtin_amdgcn_s_setprio(1);
#pragma unroll
    for (int kk = 0; kk < 2; ++kk)
#pragma unroll
      for (int mi = 0; mi < 4; ++mi)
#pragma unroll
        for (int ni = 0; ni < 2; ++ni)
          acc[mi][ni] = mfma16(aF0[mi][kk], bF0[ni][kk], acc[mi][ni]);
    __builtin_amdgcn_s_setprio(0);
    __builtin_amdgcn_s_barrier();

    // ---- ph1: quadrant (qm0,qn1). reads: bF1 (4)
    if (kt + 1 < NT) ST_A1(kt + 1);
#pragma unroll
    for (int ni = 0; ni < 2; ++ni)
#pragma unroll
      for (int kk = 0; kk < 2; ++kk)
        bF1[ni][kk] = *(const bf16x8*)&Bh[kk * 4096 + (bcol + 32 + ni * 16 + l15) * 32 + cA];
    __builtin_amdgcn_s_barrier();
    __builtin_amdgcn_s_setprio(1);
#pragma unroll
    for (int kk = 0; kk < 2; ++kk)
#pragma unroll
      for (int mi = 0; mi < 4; ++mi)
#pragma unroll
        for (int ni = 0; ni < 2; ++ni)
          acc[mi][2 + ni] = mfma16(aF0[mi][kk], bF1[ni][kk], acc[mi][2 + ni]);
    __builtin_amdgcn_s_setprio(0);
    __builtin_amdgcn_s_barrier();

    // ---- ph2: quadrant (qm1,qn1). reads: aF1 (8)
    if (kt + 2 < NT) ST_B0(kt + 2);   // B(kt) fully read before ph1's close
#pragma unroll
    for (int mi = 0; mi < 4; ++mi)
#pragma unroll
      for (int kk = 0; kk < 2; ++kk)
        aF1[mi][kk] = *(const bf16x8*)&Ah[kk * 4096 + (64 + mi * 16 + l15) * 32 + cA];
    __builtin_amdgcn_s_barrier();
    __builtin_amdgcn_s_setprio(1);
#pragma unroll
    for (int kk = 0; kk < 2; ++kk)
#pragma unroll
      for (int mi = 0; mi < 4; ++mi)
#pragma unroll
        for (int ni = 0; ni < 2; ++ni)
          acc[4 + mi][2 + ni] = mfma16(aF1[mi][kk], bF1[ni][kk], acc[4 + mi][2 + ni]);
    __builtin_amdgcn_s_setprio(0);
    __builtin_amdgcn_s_barrier();

    // ---- ph3: quadrant (qm1,qn0). reads: none (aF1 + bF0 live in regs)
    if (kt + 2 < NT) ST_A0(kt + 2);   // A(kt) fully read before ph2's close
    __builtin_amdgcn_s_setprio(1);
#pragma unroll
    for (int kk = 0; kk < 2; ++kk)
#pragma unroll
      for (int mi = 0; mi < 4; ++mi)
#pragma unroll
        for (int ni = 0; ni < 2; ++ni)
          acc[4 + mi][ni] = mfma16(aF1[mi][kk], bF0[ni][kk], acc[4 + mi][ni]);
    __builtin_amdgcn_s_setprio(0);
    if (kt < NT - 2)      asm volatile("s_waitcnt vmcnt(4)" ::: "memory");  // step kt+1 valid
    else if (kt == NT - 2) asm volatile("s_waitcnt vmcnt(0)" ::: "memory");
    __builtin_amdgcn_s_barrier();
  }

#pragma unroll
  for (int mi = 0; mi < 8; ++mi)
#pragma unroll
    for (int ni = 0; ni < 4; ++ni) {
      int row0 = bm + wr * 128 + mi * 16 + l4 * 4;
      int col  = bn + wc * 64 + ni * 16 + l15;
      if (EPI == 0) {
        u16* C = (u16*)Cout;
#pragma unroll
        for (int r = 0; r < 4; r++) C[(size_t)(row0 + r) * N + col] = f2bf(acc[mi][ni][r]);
      } else {
        float* C = (float*)Cout;
        float b = bias[col];
#pragma unroll
        for (int r = 0; r < 4; r++) {
          size_t idx = (size_t)(row0 + r) * N + col;
          C[idx] = acc[mi][ni][r] + b + resid[idx];
        }
      }
    }
}

// ---------------- Flash attention v3 (causal, LDS-staged K/V) -----------------
// 512 blocks (heavy-first qx, head = lin&31), 512 threads = 8 waves.
// Block = 128 q-rows (16/wave), KVBLK = 64. K,V tiles staged in LDS per block.
// Q,K: [h][s][160] bf16.  Vt: [h][160][s] bf16.  ctx out: [s][h*160+d] bf16.
__global__ __launch_bounds__(512, 4) void attn_kernel(
    const u16* __restrict__ Qr, const u16* __restrict__ Kr,
    const u16* __restrict__ Vt, u16* __restrict__ ctx)
{
  int lin = blockIdx.x;
  int qx = 15 - (lin >> 5);        // heavy-first over q-tiles
  int h  = lin & 31;               // same head -> same XCD (round-robin % 8)
  int q0 = qx * 128;
  int tid = threadIdx.x;
  int w = tid >> 6, l = tid & 63, l15 = l & 15, l4 = l >> 4;
  int qb = q0 + w * 16;

  __shared__ u16 Ks[64][164];      // 328B row stride: 2-way max on frag reads
  __shared__ u16 Vs[160][68];      // 136B row stride: 2-way max
  __shared__ u16 Plds[8][16][68];  // per-wave P tile

  const u16* Qh = Qr + (size_t)h * S_LEN * HDIM;
  const u16* Kh = Kr + (size_t)h * S_LEN * HDIM;
  const u16* Vh = Vt + (size_t)h * HDIM * S_LEN;

  bf16x8 aQ[5];
#pragma unroll
  for (int kc = 0; kc < 5; kc++)
    aQ[kc] = *(const bf16x8*)&Qh[(size_t)(qb + l15) * HDIM + kc * 32 + l4 * 8];

  f32x4 accO[10];
#pragma unroll
  for (int dt = 0; dt < 10; dt++) accO[dt] = f32x4{0.f, 0.f, 0.f, 0.f};
  float mrun[4], lrun[4];
#pragma unroll
  for (int r = 0; r < 4; r++) { mrun[r] = -1e30f; lrun[r] = 0.f; }

  const float c2 = 0.07905694150420949f * 1.44269504088896f;  // 1/sqrt(160)*log2(e)
  int Tend = 2 * qx + 2;           // k tiles cover k <= q0+127

  // Staging map: 2560 16B-chunks = K tile (1280: 64 rows x 20) then V tile
  // (1280: 160 rows x 8). u = tid + 512*i; 1280 is 64-aligned: no wave split.
  // ---- prologue: stage tile 0 ----
  {
    uint4 rg[5];
#pragma unroll
    for (int i = 0; i < 5; i++) {
      int u = tid + 512 * i;
      if (u < 1280) { int row = u / 20, c = u % 20;
        rg[i] = *(const uint4*)&Kh[(size_t)row * HDIM + c * 8]; }
      else { int v = u - 1280; int row = v >> 3, c = v & 7;
        rg[i] = *(const uint4*)&Vh[(size_t)row * S_LEN + c * 8]; }
    }
#pragma unroll
    for (int i = 0; i < 5; i++) {
      int u = tid + 512 * i;
      if (u < 1280) { int row = u / 20, c = u % 20; *(uint4*)&Ks[row][c * 8] = rg[i]; }
      else { int v = u - 1280; int row = v >> 3, c = v & 7; *(uint4*)&Vs[row][c * 8] = rg[i]; }
    }
  }
  __syncthreads();

  for (int t = 0; t < Tend; ++t) {
    int k0 = t * 64;
    bool more = (t + 1 < Tend);
    uint4 rg[5];
    if (more) {                     // issue next-tile loads early (T14)
      int k1 = k0 + 64;
#pragma unroll
      for (int i = 0; i < 5; i++) {
        int u = tid + 512 * i;
        if (u < 1280) { int row = u / 20, c = u % 20;
          rg[i] = *(const uint4*)&Kh[(size_t)(k1 + row) * HDIM + c * 8]; }
        else { int v = u - 1280; int row = v >> 3, c = v & 7;
          rg[i] = *(const uint4*)&Vh[(size_t)row * S_LEN + k1 + c * 8]; }
      }
    }

    if (k0 <= qb + 15) {            // wave-active (causal tile skip)
      f32x4 s_[4];
#pragma unroll
      for (int nt = 0; nt < 4; nt++) s_[nt] = f32x4{0.f, 0.f, 0.f, 0.f};

#pragma unroll
      for (int kc = 0; kc < 5; kc++) {
        bf16x8 bK[4];
#pragma unroll
        for (int nt = 0; nt < 4; nt++)
          bK[nt] = *(const bf16x8*)&Ks[nt * 16 + l15][kc * 32 + l4 * 8];
#pragma unroll
        for (int nt = 0; nt < 4; nt++) s_[nt] = mfma16(aQ[kc], bK[nt], s_[nt]);
      }

      if (k0 + 63 > qb) {           // diagonal-region mask
#pragma unroll
        for (int nt = 0; nt < 4; nt++)
#pragma unroll
          for (int r = 0; r < 4; r++) {
            int kk = k0 + nt * 16 + l15;
            int qq = qb + l4 * 4 + r;
            if (kk > qq) s_[nt][r] = -1e30f;
          }
      }

      float sf[4];
#pragma unroll
      for (int r = 0; r < 4; r++) {
        float v = fmaxf(fmaxf(s_[0][r], s_[1][r]), fmaxf(s_[2][r], s_[3][r]));
#pragma unroll
        for (int m = 1; m <= 8; m <<= 1) v = fmaxf(v, __shfl_xor(v, m));
        float mnew = fmaxf(mrun[r], v);
        sf[r] = exp2f((mrun[r] - mnew) * c2);
        mrun[r] = mnew;
      }
      float rsum[4] = {0.f, 0.f, 0.f, 0.f};
#pragma unroll
      for (int nt = 0; nt < 4; nt++)
#pragma unroll
        for (int r = 0; r < 4; r++) {
          float p = exp2f((s_[nt][r] - mrun[r]) * c2);
          s_[nt][r] = p;
          rsum[r] += p;
        }
#pragma unroll
      for (int r = 0; r < 4; r++) {
        float v = rsum[r];
#pragma unroll
        for (int m = 1; m <= 8; m <<= 1) v += __shfl_xor(v, m);
        lrun[r] = lrun[r] * sf[r] + v;
      }
#pragma unroll
      for (int dt = 0; dt < 10; dt++)
#pragma unroll
        for (int r = 0; r < 4; r++) accO[dt][r] *= sf[r];
#pragma unroll
      for (int nt = 0; nt < 4; nt++)
#pragma unroll
        for (int r = 0; r < 4; r++)
          Plds[w][l4 * 4 + r][nt * 16 + l15] = f2bf(s_[nt][r]);

      // PV: A = P (wave-local LDS), B = V rows (block LDS)
#pragma unroll
      for (int kc = 0; kc < 2; kc++) {
        bf16x8 aP = *(const bf16x8*)&Plds[w][l15][kc * 32 + l4 * 8];
        bf16x8 bV[10];
#pragma unroll
        for (int dt = 0; dt < 10; dt++)
          bV[dt] = *(const bf16x8*)&Vs[dt * 16 + l15][kc * 32 + l4 * 8];
#pragma unroll
        for (int dt = 0; dt < 10; dt++)
          accO[dt] = mfma16(aP, bV[dt], accO[dt]);
      }
    }

    __syncthreads();                // all waves done reading Ks/Vs for tile t
    if (more) {
#pragma unroll
      for (int i = 0; i < 5; i++) {
        int u = tid + 512 * i;
        if (u < 1280) { int row = u / 20, c = u % 20; *(uint4*)&Ks[row][c * 8] = rg[i]; }
        else { int v = u - 1280; int row = v >> 3, c = v & 7; *(uint4*)&Vs[row][c * 8] = rg[i]; }
      }
    }
    __syncthreads();                // tile t+1 visible
  }

  float inv[4];
#pragma unroll
  for (int r = 0; r < 4; r++) inv[r] = 1.0f / lrun[r];
#pragma unroll
  for (int dt = 0; dt < 10; dt++)
#pragma unroll
    for (int r = 0; r < 4; r++) {
      int q = qb + l4 * 4 + r;
      ctx[(size_t)q * HID + h * HDIM + dt * 16 + l15] = f2bf(accO[dt][r] * inv[r]);
    }
}

// -----------------------------------------------------------------------------
extern "C" void kernel_launch(void* const* d_in, const int* in_sizes, int n_in,
                              void* d_out, int out_size, void* d_ws, size_t ws_size,
                              hipStream_t stream) {
  const float* hs    = (const float*)d_in[0];
  const float* resid = (const float*)d_in[1];
  // d_in[2] = attention_mask (causal triu) — implied by kernel, ignored
  const float* Wq  = (const float*)d_in[3];
  const float* Wkv = (const float*)d_in[4];
  const float* Wd  = (const float*)d_in[5];
  const float* bd  = (const float*)d_in[6];
  float* out = (float*)d_out;

  char* ws = (char*)d_ws;
  const size_t SH = (size_t)S_LEN * HID;          // 10,485,760
  u16* Xb     = (u16*)(ws);                        size_t off = SH * 2;
  u16* Wqkvb  = (u16*)(ws + off);                  off += (size_t)3 * HID * HID * 2; // [Wq rows | Wkv rows]
  u16* Wdb    = (u16*)(ws + off);                  off += (size_t)HID * HID * 2;
  u16* QKVraw = (u16*)(ws + off);                  off += (size_t)S_LEN * NQKV * 2;  // [2048][15360]
  u16* Qr     = (u16*)(ws + off);                  off += SH * 2;
  u16* Kr     = (u16*)(ws + off);                  off += SH * 2;
  u16* Vt     = (u16*)(ws + off);                  off += SH * 2;
  u16* ctx    = (u16*)(ws + off);                  off += SH * 2;
  float2* tab = (float2*)(ws + off);               off += (size_t)S_LEN * 80 * 8;

  // 1) convert to bf16 (Wq then Wkv contiguously -> fused B matrix)
  cvt_bf16_kernel<<<(int)(SH / 8 / 256), 256, 0, stream>>>(hs, Xb, (int)(SH / 8));
  cvt_bf16_kernel<<<HID * HID / 8 / 256, 256, 0, stream>>>(Wq, Wqkvb, HID * HID / 8);
  cvt_bf16_kernel<<<2 * HID * HID / 8 / 256, 256, 0, stream>>>(Wkv, Wqkvb + (size_t)HID * HID, 2 * HID * HID / 8);
  cvt_bf16_kernel<<<HID * HID / 8 / 256, 256, 0, stream>>>(Wd, Wdb, HID * HID / 8);

  // 2) RoPE table
  rope_table_kernel<<<(S_LEN * 80 + 255) / 256, 256, 0, stream>>>(tab);

  // 3) fused QKV projection: [2048,15360] = Xb @ [Wq|Wkv]^T
  gemm256<0><<<dim3(NQKV / 256, S_LEN / 256), 512, 0, stream>>>(
      Xb, Wqkvb, QKVraw, S_LEN, NQKV, HID, nullptr, nullptr);

  // 4) RoPE + relayout; V transpose (all reading fused QKVraw)
  rope_apply_kernel<<<S_LEN * NHEAD * 80 / 256, 256, 0, stream>>>(QKVraw, tab, Qr, HDIM, NQKV);
  rope_apply_kernel<<<S_LEN * NHEAD * 80 / 256, 256, 0, stream>>>(QKVraw + HID, tab, Kr, 2 * HDIM, NQKV);
  vtrans_kernel<<<dim3(S_LEN / 64, NHEAD), 256, 0, stream>>>(QKVraw + HID + HDIM, Vt, NQKV);

  // 5) attention (LDS-staged, heavy-first, 128 q-rows per block)
  attn_kernel<<<512, 512, 0, stream>>>(Qr, Kr, Vt, ctx);

  // 6) output projection + bias + residual
  gemm256<1><<<dim3(HID / 256, S_LEN / 256), 512, 0, stream>>>(
      ctx, Wdb, out, S_LEN, HID, HID, bd, resid);
}

// Round 7
// 1007.700 us; speedup vs baseline: 1.1029x; 1.1029x over previous
//
#include <hip/hip_runtime.h>
#include <cmath>

typedef unsigned short u16;
typedef unsigned int   u32;

using bf16x8 = __attribute__((ext_vector_type(8))) short;   // 8 bf16 in 4 VGPRs
using f32x4  = __attribute__((ext_vector_type(4))) float;

#define S_LEN 2048
#define NHEAD 32
#define HDIM  160
#define HID   5120   // NHEAD*HDIM
#define NQKV  15360  // HID + 2*HID

__device__ __forceinline__ f32x4 mfma16(bf16x8 a, bf16x8 b, f32x4 c) {
  return __builtin_amdgcn_mfma_f32_16x16x32_bf16(a, b, c, 0, 0, 0);
}

__device__ __forceinline__ u16 f2bf(float f) {          // RNE f32->bf16
  u32 u = __builtin_bit_cast(u32, f);
  u += 0x7FFFu + ((u >> 16) & 1u);
  return (u16)(u >> 16);
}
__device__ __forceinline__ float bf2f(u16 h) {
  u32 u = ((u32)h) << 16;
  return __builtin_bit_cast(float, u);
}

// async global->LDS, 16B per lane; LDS dest is wave-uniform base + lane*16
__device__ __forceinline__ void gload16(const void* g, void* l) {
  __builtin_amdgcn_global_load_lds((const __attribute__((address_space(1))) void*)g,
                                   (__attribute__((address_space(3))) void*)l, 16, 0, 0);
}

// ---------------- f32 -> bf16 convert (vectorized, 8 elems/thread) ------------
__global__ void cvt_bf16_kernel(const float* __restrict__ in, u16* __restrict__ out, int n8) {
  int i = blockIdx.x * 256 + threadIdx.x;
  if (i >= n8) return;
  const float4* p = (const float4*)in + (size_t)i * 2;
  float4 a = p[0], b = p[1];
  uint4 o;
  o.x = (u32)f2bf(a.x) | ((u32)f2bf(a.y) << 16);
  o.y = (u32)f2bf(a.z) | ((u32)f2bf(a.w) << 16);
  o.z = (u32)f2bf(b.x) | ((u32)f2bf(b.y) << 16);
  o.w = (u32)f2bf(b.z) | ((u32)f2bf(b.w) << 16);
  ((uint4*)out)[i] = o;
}

// ---------------- RoPE table: tab[s][j] = (cos, sin), j<80 -------------------
// eff=8192 -> mscale=1.0, ntk_alpha=3, base=10000*3^(160/158).
// invf[80] hoisted to LDS (f64 pow is ~1000s of cycles; was 164k redundant calls).
// f32 trig on f64-reduced angle: err ~1e-7, negligible vs bf16 quantization.
__global__ void rope_table_kernel(float2* __restrict__ tab) {
  __shared__ double invf_s[80];
  int tid = threadIdx.x;
  if (tid < 80) {
    double base = 10000.0 * pow(3.0, 160.0 / 158.0);
    invf_s[tid] = pow(base, -((double)(2 * tid)) / 160.0);
  }
  __syncthreads();
  for (int i = blockIdx.x * 256 + tid; i < S_LEN * 80; i += gridDim.x * 256) {
    int s = i / 80, j = i % 80;
    double ang = fmod((double)s * invf_s[j], 6.283185307179586476925287);
    float a = (float)ang;
    tab[i] = make_float2(cosf(a), sinf(a));
  }
}

// ---------------- RoPE apply + head-major relayout ---------------------------
// src row layout: src[s*rowStride + h*headStride + d], d in [0,160)
// dst: dst[(h*2048 + s)*160 + d]   (bf16)
__global__ void rope_apply_kernel(const u16* __restrict__ src, const float2* __restrict__ tab,
                                  u16* __restrict__ dst, int headStride, int rowStride) {
  int i = blockIdx.x * 256 + threadIdx.x;           // over 2048*32*80 dword-pairs
  if (i >= S_LEN * NHEAD * 80) return;
  int dp = i % 80; int sh = i / 80; int h = sh % NHEAD; int s = sh / NHEAD;
  int d = 2 * dp;
  const u16* row = src + (size_t)s * rowStride + h * headStride;
  u32 q01 = *(const u32*)&row[d];
  u32 p01 = *(const u32*)&row[d < 80 ? d + 80 : d - 80];
  int j = (d < 80) ? d : d - 80;
  float2 cs0 = tab[s * 80 + j];
  float2 cs1 = tab[s * 80 + j + 1];
  float q0 = bf2f((u16)(q01 & 0xffff)), q1 = bf2f((u16)(q01 >> 16));
  float p0 = bf2f((u16)(p01 & 0xffff)), p1 = bf2f((u16)(p01 >> 16));
  float sgn = (d < 80) ? -1.f : 1.f;                // out = x*cos + rot_half(x)*sin
  float o0 = q0 * cs0.x + sgn * p0 * cs0.y;
  float o1 = q1 * cs1.x + sgn * p1 * cs1.y;
  u32 o = (u32)f2bf(o0) | ((u32)f2bf(o1) << 16);
  *(u32*)&dst[((size_t)h * S_LEN + s) * HDIM + d] = o;
}

// ---------------- V transpose: v-slice of fused QKV -> Vt[h][d][s] -----------
// src[(s)*rowStride + h*320 + 2dp] points at the V part (base pre-offset).
__global__ void vtrans_kernel(const u16* __restrict__ src, u16* __restrict__ Vt, int rowStride) {
  __shared__ u16 T[HDIM][72];                       // pad 64->72 (2-way max on reads)
  int h = blockIdx.y; int s0 = blockIdx.x * 64; int tid = threadIdx.x;
  for (int i = tid; i < 64 * 80; i += 256) {
    int s = i / 80, dp = i % 80;
    u32 v = *(const u32*)&src[(size_t)(s0 + s) * rowStride + h * 320 + 2 * dp];
    T[2 * dp][s]     = (u16)(v & 0xffff);
    T[2 * dp + 1][s] = (u16)(v >> 16);
  }
  __syncthreads();
  for (int i = tid; i < HDIM * 32; i += 256) {
    int d = i / 32, sp = i % 32;
    u32 v = (u32)T[d][2 * sp] | ((u32)T[d][2 * sp + 1] << 16);
    *(u32*)&Vt[((size_t)h * HDIM + d) * S_LEN + s0 + 2 * sp] = v;
  }
}

// ---------------- GEMM 256x256 (R5 2-phase, counted vmcnt; QKV only) ----------
// C[M,N] = A[M,K] @ B[N,K]^T, bf16 in, f32 acc. BK=64, 512 thr = 8 waves (2Mx4N),
// per-wave 128x64 out. LDS 128 KiB, st_16x32 swizzle both sides (0 conflicts, R5).
// Per K-tile: STAGE(kt+1) [8 gload_lds], vmcnt(8) -> kt landed, raw barrier,
// 24 ds_read / 64 MFMA (each frag once), raw barrier. Measured 754 TF (R5).
template<int EPI>
__global__ __launch_bounds__(512, 2) void gemm256(
    const u16* __restrict__ A, const u16* __restrict__ Bm, void* __restrict__ Cout,
    int M, int N, int K, const float* __restrict__ bias, const float* __restrict__ resid)
{
  __shared__ u16 As[2][2][8192];   // 64 KB
  __shared__ u16 Bs[2][2][8192];   // 64 KB
  int tid = threadIdx.x;
  int w = tid >> 6, l = tid & 63, l15 = l & 15, l4 = l >> 4;
  int wr = w >> 2, wc = w & 3;

  // XCD chunked swizzle (nwg % 8 == 0 guaranteed by launch)
  int nbx = gridDim.x;
  int nwg = nbx * gridDim.y;
  int lin = blockIdx.y * nbx + blockIdx.x;
  int cpx = nwg >> 3;
  int swz = (lin & 7) * cpx + (lin >> 3);
  int bm = (swz / nbx) * 256, bn = (swz % nbx) * 256;

  int srow = tid >> 2;                                  // 0..127
  int scol = ((tid & 3) * 8) ^ ((srow & 8) ? 16 : 0);   // pre-swizzled source col
  const u16* gA0 = A  + (size_t)(bm +       srow) * K + scol;
  const u16* gA1 = A  + (size_t)(bm + 128 + srow) * K + scol;
  const u16* gB0 = Bm + (size_t)(bn +       srow) * K + scol;
  const u16* gB1 = Bm + (size_t)(bn + 128 + srow) * K + scol;
  int dstoff = w * 512;                                 // elems (wave-uniform)

  f32x4 acc[8][4];
#pragma unroll
  for (int i = 0; i < 8; i++)
#pragma unroll
    for (int j = 0; j < 4; j++) acc[i][j] = f32x4{0.f, 0.f, 0.f, 0.f};

  int cA = (l4 * 8) ^ ((l15 & 8) ? 16 : 0);             // read-side swizzle (const)
  const int NT = K >> 6;

  auto STAGE = [&](int kt, int p) {
    int k0 = kt << 6;
    gload16(gA0 + k0,      &As[p][0][dstoff]);
    gload16(gA0 + k0 + 32, &As[p][0][4096 + dstoff]);
    gload16(gA1 + k0,      &As[p][1][dstoff]);
    gload16(gA1 + k0 + 32, &As[p][1][4096 + dstoff]);
    gload16(gB0 + k0,      &Bs[p][0][dstoff]);
    gload16(gB0 + k0 + 32, &Bs[p][0][4096 + dstoff]);
    gload16(gB1 + k0,      &Bs[p][1][dstoff]);
    gload16(gB1 + k0 + 32, &Bs[p][1][4096 + dstoff]);
  };

  STAGE(0, 0);
  for (int kt = 0; kt < NT; ++kt) {
    int p = kt & 1;
    if (kt + 1 < NT) {
      STAGE(kt + 1, p ^ 1);
      asm volatile("s_waitcnt vmcnt(8)" ::: "memory");   // tile kt arrived
    } else {
      asm volatile("s_waitcnt vmcnt(0)" ::: "memory");
    }
    __builtin_amdgcn_s_barrier();           // raw: no implicit vmcnt(0) drain

    const u16* Ah = &As[p][wr][0];
    const u16* Bh = &Bs[p][wc >> 1][0];
    int bcol = (wc & 1) * 64;
#pragma unroll
    for (int kk = 0; kk < 2; ++kk) {        // 2 phases/K-tile, each frag read once
      bf16x8 aF[8], bF[4];
#pragma unroll
      for (int mi = 0; mi < 8; ++mi)
        aF[mi] = *(const bf16x8*)&Ah[kk * 4096 + (mi * 16 + l15) * 32 + cA];
#pragma unroll
      for (int ni = 0; ni < 4; ++ni)
        bF[ni] = *(const bf16x8*)&Bh[kk * 4096 + (bcol + ni * 16 + l15) * 32 + cA];
      __builtin_amdgcn_s_setprio(1);
#pragma unroll
      for (int mi = 0; mi < 8; ++mi)
#pragma unroll
        for (int ni = 0; ni < 4; ++ni)
          acc[mi][ni] = mfma16(aF[mi], bF[ni], acc[mi][ni]);
      __builtin_amdgcn_s_setprio(0);
    }
    __builtin_amdgcn_s_barrier();           // all reads of tile kt done
  }

#pragma unroll
  for (int mi = 0; mi < 8; ++mi)
#pragma unroll
    for (int ni = 0; ni < 4; ++ni) {
      int row0 = bm + wr * 128 + mi * 16 + l4 * 4;
      int col  = bn + wc * 64 + ni * 16 + l15;
      if (EPI == 0) {
        u16* C = (u16*)Cout;
#pragma unroll
        for (int r = 0; r < 4; r++) C[(size_t)(row0 + r) * N + col] = f2bf(acc[mi][ni][r]);
      } else {
        float* C = (float*)Cout;
        float b = bias[col];
#pragma unroll
        for (int r = 0; r < 4; r++) {
          size_t idx = (size_t)(row0 + r) * N + col;
          C[idx] = acc[mi][ni][r] + b + resid[idx];
        }
      }
    }
}

// ---------------- GEMM 128x128 (m97 structure; proj only — 640 blocks fill GPU)
// R3-measured 694 TF with full grid; proj's N=5120 gives only 160 blocks at 256²
// (underfilled, ~250 µs) vs 640 here (~155 µs).
template<int EPI>
__global__ __launch_bounds__(256, 2) void gemm_bt(
    const u16* __restrict__ A, const u16* __restrict__ Bm, void* __restrict__ Cout,
    int M, int N, int K, const float* __restrict__ bias, const float* __restrict__ resid)
{
  int tid = threadIdx.x;
  int wv = tid >> 6, l = tid & 63, l15 = l & 15, l4 = l >> 4;
  int nbx = gridDim.x;
  int nwg = nbx * gridDim.y;
  int lin = blockIdx.y * nbx + blockIdx.x;
  int cpx = nwg >> 3;
  int swz = (lin & 7) * cpx + (lin >> 3);
  int bm = (swz / nbx) * 128, bn = (swz % nbx) * 128;

  __shared__ u16 As[128 * 32], Bs[128 * 32];
  f32x4 acc[4][4];
#pragma unroll
  for (int i = 0; i < 4; i++)
#pragma unroll
    for (int j = 0; j < 4; j++) acc[i][j] = f32x4{0.f, 0.f, 0.f, 0.f};

  int wm = (wv >> 1) * 64, wn = (wv & 1) * 64;
  const u16* gA = A + (size_t)(bm + (tid >> 2)) * K + (tid & 3) * 8;
  const u16* gB = Bm + (size_t)(bn + (tid >> 2)) * K + (tid & 3) * 8;
  u16* ldsA = As + wv * 16 * 32;
  u16* ldsB = Bs + wv * 16 * 32;

  for (int k0 = 0; k0 < K; k0 += 32) {
    __syncthreads();
    gload16(gA + k0, ldsA);
    gload16(gA + (size_t)64 * K + k0, ldsA + 64 * 32);
    gload16(gB + k0, ldsB);
    gload16(gB + (size_t)64 * K + k0, ldsB + 64 * 32);
    __syncthreads();
    bf16x8 af[4], bfr[4];
#pragma unroll
    for (int i = 0; i < 4; i++) af[i] = *(const bf16x8*)&As[(wm + i * 16 + l15) * 32 + l4 * 8];
#pragma unroll
    for (int i = 0; i < 4; i++) bfr[i] = *(const bf16x8*)&Bs[(wn + i * 16 + l15) * 32 + l4 * 8];
#pragma unroll
    for (int mi = 0; mi < 4; mi++)
#pragma unroll
      for (int ni = 0; ni < 4; ni++) acc[mi][ni] = mfma16(af[mi], bfr[ni], acc[mi][ni]);
  }

#pragma unroll
  for (int mi = 0; mi < 4; mi++)
#pragma unroll
    for (int ni = 0; ni < 4; ni++) {
      int row0 = bm + wm + mi * 16 + l4 * 4;
      int col  = bn + wn + ni * 16 + l15;
      if (EPI == 0) {
        u16* C = (u16*)Cout;
#pragma unroll
        for (int r = 0; r < 4; r++) C[(size_t)(row0 + r) * N + col] = f2bf(acc[mi][ni][r]);
      } else {
        float* C = (float*)Cout;
        float b = bias[col];
#pragma unroll
        for (int r = 0; r < 4; r++) {
          size_t idx = (size_t)(row0 + r) * N + col;
          C[idx] = acc[mi][ni][r] + b + resid[idx];
        }
      }
    }
}

// ---------------- Flash attention v4 (causal, LDS-staged K/V) -----------------
// 512 blocks, 512 threads = 8 waves, 128 q-rows/block (16/wave), KVBLK=64.
// Balance: lin<256 -> qx=15-(lin>>5) (heavy), else qx=(lin-256)>>5 (light);
// CU c hosts blocks c & c+256 -> tile sum = 36 for EVERY CU (was 20..48).
// Raw s_barrier (no vmcnt/lgkm drain — was exposing prefetch latency 2x/tile);
// the only required wait is lgkmcnt(0) after ds_writes (cross-wave visibility).
__global__ __launch_bounds__(512, 4) void attn_kernel(
    const u16* __restrict__ Qr, const u16* __restrict__ Kr,
    const u16* __restrict__ Vt, u16* __restrict__ ctx)
{
  int lin = blockIdx.x;
  int h  = lin & 31;               // same head -> same XCD (lin%8 == h%8 both halves)
  int qx = (lin < 256) ? (15 - (lin >> 5)) : ((lin - 256) >> 5);
  int q0 = qx * 128;
  int tid = threadIdx.x;
  int w = tid >> 6, l = tid & 63, l15 = l & 15, l4 = l >> 4;
  int qb = q0 + w * 16;

  __shared__ u16 Ks[64][164];      // 328B row stride: <=2-way on frag reads
  __shared__ u16 Vs[160][68];      // 136B row stride: conflict-free reads
  __shared__ u16 Plds[8][16][68];  // per-wave P tile

  const u16* Qh = Qr + (size_t)h * S_LEN * HDIM;
  const u16* Kh = Kr + (size_t)h * S_LEN * HDIM;
  const u16* Vh = Vt + (size_t)h * HDIM * S_LEN;

  bf16x8 aQ[5];
#pragma unroll
  for (int kc = 0; kc < 5; kc++)
    aQ[kc] = *(const bf16x8*)&Qh[(size_t)(qb + l15) * HDIM + kc * 32 + l4 * 8];

  f32x4 accO[10];
#pragma unroll
  for (int dt = 0; dt < 10; dt++) accO[dt] = f32x4{0.f, 0.f, 0.f, 0.f};
  float mrun[4], lrun[4];
#pragma unroll
  for (int r = 0; r < 4; r++) { mrun[r] = -1e30f; lrun[r] = 0.f; }

  const float c2 = 0.07905694150420949f * 1.44269504088896f;  // 1/sqrt(160)*log2(e)
  int Tend = 2 * qx + 2;           // k tiles cover k <= q0+127

  // Staging map: 2560 16B-chunks = K tile (1280: 64 rows x 20) then V tile
  // (1280: 160 rows x 8). u = tid + 512*i; 1280 is 64-aligned: no wave split.
  {
    uint4 rg[5];
#pragma unroll
    for (int i = 0; i < 5; i++) {
      int u = tid + 512 * i;
      if (u < 1280) { int row = u / 20, c = u % 20;
        rg[i] = *(const uint4*)&Kh[(size_t)row * HDIM + c * 8]; }
      else { int v = u - 1280; int row = v >> 3, c = v & 7;
        rg[i] = *(const uint4*)&Vh[(size_t)row * S_LEN + c * 8]; }
    }
#pragma unroll
    for (int i = 0; i < 5; i++) {
      int u = tid + 512 * i;
      if (u < 1280) { int row = u / 20, c = u % 20; *(uint4*)&Ks[row][c * 8] = rg[i]; }
      else { int v = u - 1280; int row = v >> 3, c = v & 7; *(uint4*)&Vs[row][c * 8] = rg[i]; }
    }
  }
  __syncthreads();

  for (int t = 0; t < Tend; ++t) {
    int k0 = t * 64;
    bool more = (t + 1 < Tend);
    uint4 rg[5];
    if (more) {                     // issue next-tile loads early (T14)
      int k1 = k0 + 64;
#pragma unroll
      for (int i = 0; i < 5; i++) {
        int u = tid + 512 * i;
        if (u < 1280) { int row = u / 20, c = u % 20;
          rg[i] = *(const uint4*)&Kh[(size_t)(k1 + row) * HDIM + c * 8]; }
        else { int v = u - 1280; int row = v >> 3, c = v & 7;
          rg[i] = *(const uint4*)&Vh[(size_t)row * S_LEN + k1 + c * 8]; }
      }
    }

    if (k0 <= qb + 15) {            // wave-active (causal tile skip)
      f32x4 s_[4];
#pragma unroll
      for (int nt = 0; nt < 4; nt++) s_[nt] = f32x4{0.f, 0.f, 0.f, 0.f};

#pragma unroll
      for (int kc = 0; kc < 5; kc++) {
        bf16x8 bK[4];
#pragma unroll
        for (int nt = 0; nt < 4; nt++)
          bK[nt] = *(const bf16x8*)&Ks[nt * 16 + l15][kc * 32 + l4 * 8];
        __builtin_amdgcn_s_setprio(1);
#pragma unroll
        for (int nt = 0; nt < 4; nt++) s_[nt] = mfma16(aQ[kc], bK[nt], s_[nt]);
        __builtin_amdgcn_s_setprio(0);
      }

      if (k0 + 63 > qb) {           // diagonal-region mask
#pragma unroll
        for (int nt = 0; nt < 4; nt++)
#pragma unroll
          for (int r = 0; r < 4; r++) {
            int kk = k0 + nt * 16 + l15;
            int qq = qb + l4 * 4 + r;
            if (kk > qq) s_[nt][r] = -1e30f;
          }
      }

      float sf[4];
#pragma unroll
      for (int r = 0; r < 4; r++) {
        float v = fmaxf(fmaxf(s_[0][r], s_[1][r]), fmaxf(s_[2][r], s_[3][r]));
#pragma unroll
        for (int m = 1; m <= 8; m <<= 1) v = fmaxf(v, __shfl_xor(v, m));
        float mnew = fmaxf(mrun[r], v);
        sf[r] = exp2f((mrun[r] - mnew) * c2);
        mrun[r] = mnew;
      }
      float rsum[4] = {0.f, 0.f, 0.f, 0.f};
#pragma unroll
      for (int nt = 0; nt < 4; nt++)
#pragma unroll
        for (int r = 0; r < 4; r++) {
          float p = exp2f((s_[nt][r] - mrun[r]) * c2);
          s_[nt][r] = p;
          rsum[r] += p;
        }
#pragma unroll
      for (int r = 0; r < 4; r++) {
        float v = rsum[r];
#pragma unroll
        for (int m = 1; m <= 8; m <<= 1) v += __shfl_xor(v, m);
        lrun[r] = lrun[r] * sf[r] + v;
      }
#pragma unroll
      for (int dt = 0; dt < 10; dt++)
#pragma unroll
        for (int r = 0; r < 4; r++) accO[dt][r] *= sf[r];
#pragma unroll
      for (int nt = 0; nt < 4; nt++)
#pragma unroll
        for (int r = 0; r < 4; r++)
          Plds[w][l4 * 4 + r][nt * 16 + l15] = f2bf(s_[nt][r]);

      // PV: A = P (wave-local LDS), B = V rows (block LDS)
#pragma unroll
      for (int kc = 0; kc < 2; kc++) {
        bf16x8 aP = *(const bf16x8*)&Plds[w][l15][kc * 32 + l4 * 8];
        bf16x8 bV[10];
#pragma unroll
        for (int dt = 0; dt < 10; dt++)
          bV[dt] = *(const bf16x8*)&Vs[dt * 16 + l15][kc * 32 + l4 * 8];
        __builtin_amdgcn_s_setprio(1);
#pragma unroll
        for (int dt = 0; dt < 10; dt++)
          accO[dt] = mfma16(aP, bV[dt], accO[dt]);
        __builtin_amdgcn_s_setprio(0);
      }
    }

    // Raw barrier: all waves' ds_reads of Ks/Vs for tile t are complete (their
    // results were consumed by MFMAs above; compiler inserts lgkmcnt before use).
    // No vmcnt drain here — rg prefetch stays in flight.
    __builtin_amdgcn_s_barrier();
    if (more) {
#pragma unroll
      for (int i = 0; i < 5; i++) {
        int u = tid + 512 * i;
        if (u < 1280) { int row = u / 20, c = u % 20; *(uint4*)&Ks[row][c * 8] = rg[i]; }
        else { int v = u - 1280; int row = v >> 3, c = v & 7; *(uint4*)&Vs[row][c * 8] = rg[i]; }
      }
      asm volatile("s_waitcnt lgkmcnt(0)" ::: "memory");  // writes visible to other waves
    }
    __builtin_amdgcn_s_barrier();
  }

  float inv[4];
#pragma unroll
  for (int r = 0; r < 4; r++) inv[r] = 1.0f / lrun[r];
#pragma unroll
  for (int dt = 0; dt < 10; dt++)
#pragma unroll
    for (int r = 0; r < 4; r++) {
      int q = qb + l4 * 4 + r;
      ctx[(size_t)q * HID + h * HDIM + dt * 16 + l15] = f2bf(accO[dt][r] * inv[r]);
    }
}

// -----------------------------------------------------------------------------
extern "C" void kernel_launch(void* const* d_in, const int* in_sizes, int n_in,
                              void* d_out, int out_size, void* d_ws, size_t ws_size,
                              hipStream_t stream) {
  const float* hs    = (const float*)d_in[0];
  const float* resid = (const float*)d_in[1];
  // d_in[2] = attention_mask (causal triu) — implied by kernel, ignored
  const float* Wq  = (const float*)d_in[3];
  const float* Wkv = (const float*)d_in[4];
  const float* Wd  = (const float*)d_in[5];
  const float* bd  = (const float*)d_in[6];
  float* out = (float*)d_out;

  char* ws = (char*)d_ws;
  const size_t SH = (size_t)S_LEN * HID;          // 10,485,760
  u16* Xb     = (u16*)(ws);                        size_t off = SH * 2;
  u16* Wqkvb  = (u16*)(ws + off);                  off += (size_t)3 * HID * HID * 2; // [Wq rows | Wkv rows]
  u16* Wdb    = (u16*)(ws + off);                  off += (size_t)HID * HID * 2;
  u16* QKVraw = (u16*)(ws + off);                  off += (size_t)S_LEN * NQKV * 2;  // [2048][15360]
  u16* Qr     = (u16*)(ws + off);                  off += SH * 2;
  u16* Kr     = (u16*)(ws + off);                  off += SH * 2;
  u16* Vt     = (u16*)(ws + off);                  off += SH * 2;
  u16* ctx    = (u16*)(ws + off);                  off += SH * 2;
  float2* tab = (float2*)(ws + off);               off += (size_t)S_LEN * 80 * 8;

  // 1) convert to bf16 (Wq then Wkv contiguously -> fused B matrix)
  cvt_bf16_kernel<<<(int)(SH / 8 / 256), 256, 0, stream>>>(hs, Xb, (int)(SH / 8));
  cvt_bf16_kernel<<<HID * HID / 8 / 256, 256, 0, stream>>>(Wq, Wqkvb, HID * HID / 8);
  cvt_bf16_kernel<<<2 * HID * HID / 8 / 256, 256, 0, stream>>>(Wkv, Wqkvb + (size_t)HID * HID, 2 * HID * HID / 8);
  cvt_bf16_kernel<<<HID * HID / 8 / 256, 256, 0, stream>>>(Wd, Wdb, HID * HID / 8);

  // 2) RoPE table
  rope_table_kernel<<<64, 256, 0, stream>>>(tab);

  // 3) fused QKV projection: [2048,15360] = Xb @ [Wq|Wkv]^T
  gemm256<0><<<dim3(NQKV / 256, S_LEN / 256), 512, 0, stream>>>(
      Xb, Wqkvb, QKVraw, S_LEN, NQKV, HID, nullptr, nullptr);

  // 4) RoPE + relayout; V transpose (all reading fused QKVraw)
  rope_apply_kernel<<<S_LEN * NHEAD * 80 / 256, 256, 0, stream>>>(QKVraw, tab, Qr, HDIM, NQKV);
  rope_apply_kernel<<<S_LEN * NHEAD * 80 / 256, 256, 0, stream>>>(QKVraw + HID, tab, Kr, 2 * HDIM, NQKV);
  vtrans_kernel<<<dim3(S_LEN / 64, NHEAD), 256, 0, stream>>>(QKVraw + HID + HDIM, Vt, NQKV);

  // 5) attention (balanced pairing, raw barriers, 128 q-rows per block)
  attn_kernel<<<512, 512, 0, stream>>>(Qr, Kr, Vt, ctx);

  // 6) output projection + bias + residual (128² tile: 640 blocks fill the GPU)
  gemm_bt<1><<<dim3(HID / 128, S_LEN / 128), 256, 0, stream>>>(
      ctx, Wdb, out, S_LEN, HID, HID, bd, resid);
}

// Round 8
// 980.761 us; speedup vs baseline: 1.1331x; 1.0275x over previous
//
#include <hip/hip_runtime.h>
#include <cmath>

typedef unsigned short u16;
typedef unsigned int   u32;

using bf16x8 = __attribute__((ext_vector_type(8))) short;   // 8 bf16 in 4 VGPRs
using f32x4  = __attribute__((ext_vector_type(4))) float;

#define S_LEN 2048
#define NHEAD 32
#define HDIM  160
#define HID   5120   // NHEAD*HDIM
#define NQKV  15360  // HID + 2*HID

__device__ __forceinline__ f32x4 mfma16(bf16x8 a, bf16x8 b, f32x4 c) {
  return __builtin_amdgcn_mfma_f32_16x16x32_bf16(a, b, c, 0, 0, 0);
}

__device__ __forceinline__ u16 f2bf(float f) {          // RNE f32->bf16
  u32 u = __builtin_bit_cast(u32, f);
  u += 0x7FFFu + ((u >> 16) & 1u);
  return (u16)(u >> 16);
}
__device__ __forceinline__ float bf2f(u16 h) {
  u32 u = ((u32)h) << 16;
  return __builtin_bit_cast(float, u);
}

// async global->LDS, 16B per lane; LDS dest is wave-uniform base + lane*16
__device__ __forceinline__ void gload16(const void* g, void* l) {
  __builtin_amdgcn_global_load_lds((const __attribute__((address_space(1))) void*)g,
                                   (__attribute__((address_space(3))) void*)l, 16, 0, 0);
}

// ---------------- f32 -> bf16 convert (vectorized, 8 elems/thread) ------------
__global__ void cvt_bf16_kernel(const float* __restrict__ in, u16* __restrict__ out, int n8) {
  int i = blockIdx.x * 256 + threadIdx.x;
  if (i >= n8) return;
  const float4* p = (const float4*)in + (size_t)i * 2;
  float4 a = p[0], b = p[1];
  uint4 o;
  o.x = (u32)f2bf(a.x) | ((u32)f2bf(a.y) << 16);
  o.y = (u32)f2bf(a.z) | ((u32)f2bf(a.w) << 16);
  o.z = (u32)f2bf(b.x) | ((u32)f2bf(b.y) << 16);
  o.w = (u32)f2bf(b.z) | ((u32)f2bf(b.w) << 16);
  ((uint4*)out)[i] = o;
}

// ---------------- RoPE table: tab[s][j] = (cos, sin), j<80 -------------------
// eff=8192 -> mscale=1.0, ntk_alpha=3, base=10000*3^(160/158).
__global__ void rope_table_kernel(float2* __restrict__ tab) {
  __shared__ double invf_s[80];
  int tid = threadIdx.x;
  if (tid < 80) {
    double base = 10000.0 * pow(3.0, 160.0 / 158.0);
    invf_s[tid] = pow(base, -((double)(2 * tid)) / 160.0);
  }
  __syncthreads();
  for (int i = blockIdx.x * 256 + tid; i < S_LEN * 80; i += gridDim.x * 256) {
    int s = i / 80, j = i % 80;
    double ang = fmod((double)s * invf_s[j], 6.283185307179586476925287);
    float a = (float)ang;
    tab[i] = make_float2(cosf(a), sinf(a));
  }
}

// ---------------- RoPE apply + head-major relayout ---------------------------
__global__ void rope_apply_kernel(const u16* __restrict__ src, const float2* __restrict__ tab,
                                  u16* __restrict__ dst, int headStride, int rowStride) {
  int i = blockIdx.x * 256 + threadIdx.x;           // over 2048*32*80 dword-pairs
  if (i >= S_LEN * NHEAD * 80) return;
  int dp = i % 80; int sh = i / 80; int h = sh % NHEAD; int s = sh / NHEAD;
  int d = 2 * dp;
  const u16* row = src + (size_t)s * rowStride + h * headStride;
  u32 q01 = *(const u32*)&row[d];
  u32 p01 = *(const u32*)&row[d < 80 ? d + 80 : d - 80];
  int j = (d < 80) ? d : d - 80;
  float2 cs0 = tab[s * 80 + j];
  float2 cs1 = tab[s * 80 + j + 1];
  float q0 = bf2f((u16)(q01 & 0xffff)), q1 = bf2f((u16)(q01 >> 16));
  float p0 = bf2f((u16)(p01 & 0xffff)), p1 = bf2f((u16)(p01 >> 16));
  float sgn = (d < 80) ? -1.f : 1.f;                // out = x*cos + rot_half(x)*sin
  float o0 = q0 * cs0.x + sgn * p0 * cs0.y;
  float o1 = q1 * cs1.x + sgn * p1 * cs1.y;
  u32 o = (u32)f2bf(o0) | ((u32)f2bf(o1) << 16);
  *(u32*)&dst[((size_t)h * S_LEN + s) * HDIM + d] = o;
}

// ---------------- V transpose: v-slice of fused QKV -> Vt[h][d][s] -----------
__global__ void vtrans_kernel(const u16* __restrict__ src, u16* __restrict__ Vt, int rowStride) {
  __shared__ u16 T[HDIM][72];                       // pad 64->72 (2-way max on reads)
  int h = blockIdx.y; int s0 = blockIdx.x * 64; int tid = threadIdx.x;
  for (int i = tid; i < 64 * 80; i += 256) {
    int s = i / 80, dp = i % 80;
    u32 v = *(const u32*)&src[(size_t)(s0 + s) * rowStride + h * 320 + 2 * dp];
    T[2 * dp][s]     = (u16)(v & 0xffff);
    T[2 * dp + 1][s] = (u16)(v >> 16);
  }
  __syncthreads();
  for (int i = tid; i < HDIM * 32; i += 256) {
    int d = i / 32, sp = i % 32;
    u32 v = (u32)T[d][2 * sp] | ((u32)T[d][2 * sp + 1] << 16);
    *(u32*)&Vt[((size_t)h * HDIM + d) * S_LEN + s0 + 2 * sp] = v;
  }
}

// ---------------- GEMM 256x256, m201-faithful 8-phase (T2+T3+T4+T5) -----------
// C[M,N] = A[M,K] @ B[N,K]^T, bf16 in, f32 acc. BK=64, 512 thr = 8 waves (2Mx4N).
// LDS: As/Bs[2 dbuf][2 kk-half][256 rows x 32 cols] (16 KB units), st_16x32
// swizzle both sides (rule #21; R5-verified 0 conflicts). Staging UNIT =
// (matrix, kk-half) covering all 256 rows -> unit needed at phase p lands
// earliest. Stream order per tile [B0,A0,B1,A1], offset: kt.ph0 issues kt+1's
// A1; ph1-3 issue kt+2's B0/A0/B1. vmcnt(6) ONCE per K-tile at ph3 proves kt+1
// fully resident (last 3 outstanding units are kt+2's). Every overwrite lands
// after its region's last-reader barrier (derivation in R8 notes).
// Phases (kk, mi-half): ds_reads 8/4/8/4, 16 MFMA each under setprio.
template<int EPI>
__global__ __launch_bounds__(512, 2) void gemm256(
    const u16* __restrict__ A, const u16* __restrict__ Bm, void* __restrict__ Cout,
    int M, int N, int K, const float* __restrict__ bias, const float* __restrict__ resid)
{
  __shared__ u16 As[2][2][8192];   // [dbuf][kk][256*32]  64 KB
  __shared__ u16 Bs[2][2][8192];   // 64 KB
  int tid = threadIdx.x;
  int w = tid >> 6, l = tid & 63, l15 = l & 15, l4 = l >> 4;
  int wr = w >> 2, wc = w & 3;

  // XCD chunked swizzle (nwg % 8 == 0 guaranteed by launch)
  int nbx = gridDim.x;
  int nwg = nbx * gridDim.y;
  int lin = blockIdx.y * nbx + blockIdx.x;
  int cpx = nwg >> 3;
  int swz = (lin & 7) * cpx + (lin >> 3);
  int bm = (swz / nbx) * 256, bn = (swz % nbx) * 256;

  int srow = tid >> 2;                                  // 0..127
  int scol = ((tid & 3) * 8) ^ ((srow & 8) ? 16 : 0);   // pre-swizzled source col
  const u16* gAr = A  + (size_t)(bm + srow) * K + scol;
  const u16* gBr = Bm + (size_t)(bn + srow) * K + scol;
  int w512 = w * 512;                                   // wave-uniform dest (elems)

  f32x4 acc[8][4];
#pragma unroll
  for (int i = 0; i < 8; i++)
#pragma unroll
    for (int j = 0; j < 4; j++) acc[i][j] = f32x4{0.f, 0.f, 0.f, 0.f};

  int cA = (l4 * 8) ^ ((l15 & 8) ? 16 : 0);             // read-side swizzle (const)
  const int NT = K >> 6;
  int arow = wr * 128;                                  // wave A row base
  int brow = (wc >> 1) * 128 + (wc & 1) * 64;           // wave B row base

  auto STA = [&](int kt, int kk) { int p = kt & 1, ko = (kt << 6) + (kk << 5);
    gload16(gAr + ko, &As[p][kk][w512]);
    gload16(gAr + (size_t)128 * K + ko, &As[p][kk][4096 + w512]); };
  auto STB = [&](int kt, int kk) { int p = kt & 1, ko = (kt << 6) + (kk << 5);
    gload16(gBr + ko, &Bs[p][kk][w512]);
    gload16(gBr + (size_t)128 * K + ko, &Bs[p][kk][4096 + w512]); };

  // prologue: K0 complete + K1's first 3 units (stream order [B0,A0,B1,A1])
  STB(0, 0); STA(0, 0); STB(0, 1); STA(0, 1);
  if (NT > 1) { STB(1, 0); STA(1, 0); STB(1, 1); }
  asm volatile("s_waitcnt vmcnt(6)" ::: "memory");      // K0's 4 units landed
  __builtin_amdgcn_s_barrier();

  for (int kt = 0; kt < NT; ++kt) {
    int p = kt & 1;
    bf16x8 aF[4], bF0[4], bF1[4];

    // ---- ph0: kk0, mi 0-3 (8 ds_reads)
    if (kt + 1 < NT) STA(kt + 1, 1);                    // kt+1's A_kk1 (last unit)
#pragma unroll
    for (int mi = 0; mi < 4; ++mi)
      aF[mi] = *(const bf16x8*)&As[p][0][(arow + mi * 16 + l15) * 32 + cA];
#pragma unroll
    for (int ni = 0; ni < 4; ++ni)
      bF0[ni] = *(const bf16x8*)&Bs[p][0][(brow + ni * 16 + l15) * 32 + cA];
    __builtin_amdgcn_s_barrier();
    __builtin_amdgcn_s_setprio(1);
#pragma unroll
    for (int mi = 0; mi < 4; ++mi)
#pragma unroll
      for (int ni = 0; ni < 4; ++ni)
        acc[mi][ni] = mfma16(aF[mi], bF0[ni], acc[mi][ni]);
    __builtin_amdgcn_s_setprio(0);
    __builtin_amdgcn_s_barrier();

    // ---- ph1: kk0, mi 4-7 (4 ds_reads; bF0 reused from regs)
    if (kt + 2 < NT) STB(kt + 2, 0);                    // B_kk0(kt) dead after ph0
#pragma unroll
    for (int mi = 0; mi < 4; ++mi)
      aF[mi] = *(const bf16x8*)&As[p][0][(arow + 64 + mi * 16 + l15) * 32 + cA];
    __builtin_amdgcn_s_barrier();
    __builtin_amdgcn_s_setprio(1);
#pragma unroll
    for (int mi = 0; mi < 4; ++mi)
#pragma unroll
      for (int ni = 0; ni < 4; ++ni)
        acc[4 + mi][ni] = mfma16(aF[mi], bF0[ni], acc[4 + mi][ni]);
    __builtin_amdgcn_s_setprio(0);
    __builtin_amdgcn_s_barrier();

    // ---- ph2: kk1, mi 0-3 (8 ds_reads)
    if (kt + 2 < NT) STA(kt + 2, 0);                    // A_kk0(kt) dead after ph1
#pragma unroll
    for (int mi = 0; mi < 4; ++mi)
      aF[mi] = *(const bf16x8*)&As[p][1][(arow + mi * 16 + l15) * 32 + cA];
#pragma unroll
    for (int ni = 0; ni < 4; ++ni)
      bF1[ni] = *(const bf16x8*)&Bs[p][1][(brow + ni * 16 + l15) * 32 + cA];
    __builtin_amdgcn_s_barrier();
    __builtin_amdgcn_s_setprio(1);
#pragma unroll
    for (int mi = 0; mi < 4; ++mi)
#pragma unroll
      for (int ni = 0; ni < 4; ++ni)
        acc[mi][ni] = mfma16(aF[mi], bF1[ni], acc[mi][ni]);
    __builtin_amdgcn_s_setprio(0);
    __builtin_amdgcn_s_barrier();

    // ---- ph3: kk1, mi 4-7 (4 ds_reads) + the ONE counted wait per K-tile
    if (kt + 2 < NT) STB(kt + 2, 1);                    // B_kk1(kt) dead after ph2
#pragma unroll
    for (int mi = 0; mi < 4; ++mi)
      aF[mi] = *(const bf16x8*)&As[p][1][(arow + 64 + mi * 16 + l15) * 32 + cA];
    __builtin_amdgcn_s_barrier();
    __builtin_amdgcn_s_setprio(1);
#pragma unroll
    for (int mi = 0; mi < 4; ++mi)
#pragma unroll
      for (int ni = 0; ni < 4; ++ni)
        acc[4 + mi][ni] = mfma16(aF[mi], bF1[ni], acc[4 + mi][ni]);
    __builtin_amdgcn_s_setprio(0);
    if (kt + 2 < NT)      asm volatile("s_waitcnt vmcnt(6)" ::: "memory");
    else if (kt + 1 < NT) asm volatile("s_waitcnt vmcnt(0)" ::: "memory");
    __builtin_amdgcn_s_barrier();
  }

#pragma unroll
  for (int mi = 0; mi < 8; ++mi)
#pragma unroll
    for (int ni = 0; ni < 4; ++ni) {
      int row0 = bm + wr * 128 + mi * 16 + l4 * 4;
      int col  = bn + wc * 64 + ni * 16 + l15;
      if (EPI == 0) {
        u16* C = (u16*)Cout;
#pragma unroll
        for (int r = 0; r < 4; r++) C[(size_t)(row0 + r) * N + col] = f2bf(acc[mi][ni][r]);
      } else {
        float* C = (float*)Cout;
        float b = bias[col];
#pragma unroll
        for (int r = 0; r < 4; r++) {
          size_t idx = (size_t)(row0 + r) * N + col;
          C[idx] = acc[mi][ni][r] + b + resid[idx];
        }
      }
    }
}

// ---------------- GEMM 128x128 (m97 structure; proj only — 640 blocks fill GPU)
template<int EPI>
__global__ __launch_bounds__(256, 2) void gemm_bt(
    const u16* __restrict__ A, const u16* __restrict__ Bm, void* __restrict__ Cout,
    int M, int N, int K, const float* __restrict__ bias, const float* __restrict__ resid)
{
  int tid = threadIdx.x;
  int wv = tid >> 6, l = tid & 63, l15 = l & 15, l4 = l >> 4;
  int nbx = gridDim.x;
  int nwg = nbx * gridDim.y;
  int lin = blockIdx.y * nbx + blockIdx.x;
  int cpx = nwg >> 3;
  int swz = (lin & 7) * cpx + (lin >> 3);
  int bm = (swz / nbx) * 128, bn = (swz % nbx) * 128;

  __shared__ u16 As[128 * 32], Bs[128 * 32];
  f32x4 acc[4][4];
#pragma unroll
  for (int i = 0; i < 4; i++)
#pragma unroll
    for (int j = 0; j < 4; j++) acc[i][j] = f32x4{0.f, 0.f, 0.f, 0.f};

  int wm = (wv >> 1) * 64, wn = (wv & 1) * 64;
  const u16* gA = A + (size_t)(bm + (tid >> 2)) * K + (tid & 3) * 8;
  const u16* gB = Bm + (size_t)(bn + (tid >> 2)) * K + (tid & 3) * 8;
  u16* ldsA = As + wv * 16 * 32;
  u16* ldsB = Bs + wv * 16 * 32;

  for (int k0 = 0; k0 < K; k0 += 32) {
    __syncthreads();
    gload16(gA + k0, ldsA);
    gload16(gA + (size_t)64 * K + k0, ldsA + 64 * 32);
    gload16(gB + k0, ldsB);
    gload16(gB + (size_t)64 * K + k0, ldsB + 64 * 32);
    __syncthreads();
    bf16x8 af[4], bfr[4];
#pragma unroll
    for (int i = 0; i < 4; i++) af[i] = *(const bf16x8*)&As[(wm + i * 16 + l15) * 32 + l4 * 8];
#pragma unroll
    for (int i = 0; i < 4; i++) bfr[i] = *(const bf16x8*)&Bs[(wn + i * 16 + l15) * 32 + l4 * 8];
#pragma unroll
    for (int mi = 0; mi < 4; mi++)
#pragma unroll
      for (int ni = 0; ni < 4; ni++) acc[mi][ni] = mfma16(af[mi], bfr[ni], acc[mi][ni]);
  }

#pragma unroll
  for (int mi = 0; mi < 4; mi++)
#pragma unroll
    for (int ni = 0; ni < 4; ni++) {
      int row0 = bm + wm + mi * 16 + l4 * 4;
      int col  = bn + wn + ni * 16 + l15;
      if (EPI == 0) {
        u16* C = (u16*)Cout;
#pragma unroll
        for (int r = 0; r < 4; r++) C[(size_t)(row0 + r) * N + col] = f2bf(acc[mi][ni][r]);
      } else {
        float* C = (float*)Cout;
        float b = bias[col];
#pragma unroll
        for (int r = 0; r < 4; r++) {
          size_t idx = (size_t)(row0 + r) * N + col;
          C[idx] = acc[mi][ni][r] + b + resid[idx];
        }
      }
    }
}

// ---------------- Flash attention v4 (causal, LDS-staged K/V) -----------------
__global__ __launch_bounds__(512, 4) void attn_kernel(
    const u16* __restrict__ Qr, const u16* __restrict__ Kr,
    const u16* __restrict__ Vt, u16* __restrict__ ctx)
{
  int lin = blockIdx.x;
  int h  = lin & 31;               // same head -> same XCD (lin%8 == h%8 both halves)
  int qx = (lin < 256) ? (15 - (lin >> 5)) : ((lin - 256) >> 5);
  int q0 = qx * 128;
  int tid = threadIdx.x;
  int w = tid >> 6, l = tid & 63, l15 = l & 15, l4 = l >> 4;
  int qb = q0 + w * 16;

  __shared__ u16 Ks[64][164];      // 328B row stride: <=2-way on frag reads
  __shared__ u16 Vs[160][68];      // 136B row stride: conflict-free reads
  __shared__ u16 Plds[8][16][68];  // per-wave P tile

  const u16* Qh = Qr + (size_t)h * S_LEN * HDIM;
  const u16* Kh = Kr + (size_t)h * S_LEN * HDIM;
  const u16* Vh = Vt + (size_t)h * HDIM * S_LEN;

  bf16x8 aQ[5];
#pragma unroll
  for (int kc = 0; kc < 5; kc++)
    aQ[kc] = *(const bf16x8*)&Qh[(size_t)(qb + l15) * HDIM + kc * 32 + l4 * 8];

  f32x4 accO[10];
#pragma unroll
  for (int dt = 0; dt < 10; dt++) accO[dt] = f32x4{0.f, 0.f, 0.f, 0.f};
  float mrun[4], lrun[4];
#pragma unroll
  for (int r = 0; r < 4; r++) { mrun[r] = -1e30f; lrun[r] = 0.f; }

  const float c2 = 0.07905694150420949f * 1.44269504088896f;  // 1/sqrt(160)*log2(e)
  int Tend = 2 * qx + 2;           // k tiles cover k <= q0+127

  {
    uint4 rg[5];
#pragma unroll
    for (int i = 0; i < 5; i++) {
      int u = tid + 512 * i;
      if (u < 1280) { int row = u / 20, c = u % 20;
        rg[i] = *(const uint4*)&Kh[(size_t)row * HDIM + c * 8]; }
      else { int v = u - 1280; int row = v >> 3, c = v & 7;
        rg[i] = *(const uint4*)&Vh[(size_t)row * S_LEN + c * 8]; }
    }
#pragma unroll
    for (int i = 0; i < 5; i++) {
      int u = tid + 512 * i;
      if (u < 1280) { int row = u / 20, c = u % 20; *(uint4*)&Ks[row][c * 8] = rg[i]; }
      else { int v = u - 1280; int row = v >> 3, c = v & 7; *(uint4*)&Vs[row][c * 8] = rg[i]; }
    }
  }
  __syncthreads();

  for (int t = 0; t < Tend; ++t) {
    int k0 = t * 64;
    bool more = (t + 1 < Tend);
    uint4 rg[5];
    if (more) {                     // issue next-tile loads early (T14)
      int k1 = k0 + 64;
#pragma unroll
      for (int i = 0; i < 5; i++) {
        int u = tid + 512 * i;
        if (u < 1280) { int row = u / 20, c = u % 20;
          rg[i] = *(const uint4*)&Kh[(size_t)(k1 + row) * HDIM + c * 8]; }
        else { int v = u - 1280; int row = v >> 3, c = v & 7;
          rg[i] = *(const uint4*)&Vh[(size_t)row * S_LEN + k1 + c * 8]; }
      }
    }

    if (k0 <= qb + 15) {            // wave-active (causal tile skip)
      f32x4 s_[4];
#pragma unroll
      for (int nt = 0; nt < 4; nt++) s_[nt] = f32x4{0.f, 0.f, 0.f, 0.f};

#pragma unroll
      for (int kc = 0; kc < 5; kc++) {
        bf16x8 bK[4];
#pragma unroll
        for (int nt = 0; nt < 4; nt++)
          bK[nt] = *(const bf16x8*)&Ks[nt * 16 + l15][kc * 32 + l4 * 8];
        __builtin_amdgcn_s_setprio(1);
#pragma unroll
        for (int nt = 0; nt < 4; nt++) s_[nt] = mfma16(aQ[kc], bK[nt], s_[nt]);
        __builtin_amdgcn_s_setprio(0);
      }

      if (k0 + 63 > qb) {           // diagonal-region mask
#pragma unroll
        for (int nt = 0; nt < 4; nt++)
#pragma unroll
          for (int r = 0; r < 4; r++) {
            int kk = k0 + nt * 16 + l15;
            int qq = qb + l4 * 4 + r;
            if (kk > qq) s_[nt][r] = -1e30f;
          }
      }

      float sf[4];
#pragma unroll
      for (int r = 0; r < 4; r++) {
        float v = fmaxf(fmaxf(s_[0][r], s_[1][r]), fmaxf(s_[2][r], s_[3][r]));
#pragma unroll
        for (int m = 1; m <= 8; m <<= 1) v = fmaxf(v, __shfl_xor(v, m));
        float mnew = fmaxf(mrun[r], v);
        sf[r] = exp2f((mrun[r] - mnew) * c2);
        mrun[r] = mnew;
      }
      float rsum[4] = {0.f, 0.f, 0.f, 0.f};
#pragma unroll
      for (int nt = 0; nt < 4; nt++)
#pragma unroll
        for (int r = 0; r < 4; r++) {
          float p = exp2f((s_[nt][r] - mrun[r]) * c2);
          s_[nt][r] = p;
          rsum[r] += p;
        }
#pragma unroll
      for (int r = 0; r < 4; r++) {
        float v = rsum[r];
#pragma unroll
        for (int m = 1; m <= 8; m <<= 1) v += __shfl_xor(v, m);
        lrun[r] = lrun[r] * sf[r] + v;
      }
#pragma unroll
      for (int dt = 0; dt < 10; dt++)
#pragma unroll
        for (int r = 0; r < 4; r++) accO[dt][r] *= sf[r];
#pragma unroll
      for (int nt = 0; nt < 4; nt++)
#pragma unroll
        for (int r = 0; r < 4; r++)
          Plds[w][l4 * 4 + r][nt * 16 + l15] = f2bf(s_[nt][r]);

      // PV: A = P (wave-local LDS), B = V rows (block LDS)
#pragma unroll
      for (int kc = 0; kc < 2; kc++) {
        bf16x8 aP = *(const bf16x8*)&Plds[w][l15][kc * 32 + l4 * 8];
        bf16x8 bV[10];
#pragma unroll
        for (int dt = 0; dt < 10; dt++)
          bV[dt] = *(const bf16x8*)&Vs[dt * 16 + l15][kc * 32 + l4 * 8];
        __builtin_amdgcn_s_setprio(1);
#pragma unroll
        for (int dt = 0; dt < 10; dt++)
          accO[dt] = mfma16(aP, bV[dt], accO[dt]);
        __builtin_amdgcn_s_setprio(0);
      }
    }

    __builtin_amdgcn_s_barrier();
    if (more) {
#pragma unroll
      for (int i = 0; i < 5; i++) {
        int u = tid + 512 * i;
        if (u < 1280) { int row = u / 20, c = u % 20; *(uint4*)&Ks[row][c * 8] = rg[i]; }
        else { int v = u - 1280; int row = v >> 3, c = v & 7; *(uint4*)&Vs[row][c * 8] = rg[i]; }
      }
      asm volatile("s_waitcnt lgkmcnt(0)" ::: "memory");  // writes visible to other waves
    }
    __builtin_amdgcn_s_barrier();
  }

  float inv[4];
#pragma unroll
  for (int r = 0; r < 4; r++) inv[r] = 1.0f / lrun[r];
#pragma unroll
  for (int dt = 0; dt < 10; dt++)
#pragma unroll
    for (int r = 0; r < 4; r++) {
      int q = qb + l4 * 4 + r;
      ctx[(size_t)q * HID + h * HDIM + dt * 16 + l15] = f2bf(accO[dt][r] * inv[r]);
    }
}

// -----------------------------------------------------------------------------
extern "C" void kernel_launch(void* const* d_in, const int* in_sizes, int n_in,
                              void* d_out, int out_size, void* d_ws, size_t ws_size,
                              hipStream_t stream) {
  const float* hs    = (const float*)d_in[0];
  const float* resid = (const float*)d_in[1];
  // d_in[2] = attention_mask (causal triu) — implied by kernel, ignored
  const float* Wq  = (const float*)d_in[3];
  const float* Wkv = (const float*)d_in[4];
  const float* Wd  = (const float*)d_in[5];
  const float* bd  = (const float*)d_in[6];
  float* out = (float*)d_out;

  char* ws = (char*)d_ws;
  const size_t SH = (size_t)S_LEN * HID;          // 10,485,760
  u16* Xb     = (u16*)(ws);                        size_t off = SH * 2;
  u16* Wqkvb  = (u16*)(ws + off);                  off += (size_t)3 * HID * HID * 2; // [Wq rows | Wkv rows]
  u16* Wdb    = (u16*)(ws + off);                  off += (size_t)HID * HID * 2;
  u16* QKVraw = (u16*)(ws + off);                  off += (size_t)S_LEN * NQKV * 2;  // [2048][15360]
  u16* Qr     = (u16*)(ws + off);                  off += SH * 2;
  u16* Kr     = (u16*)(ws + off);                  off += SH * 2;
  u16* Vt     = (u16*)(ws + off);                  off += SH * 2;
  u16* ctx    = (u16*)(ws + off);                  off += SH * 2;
  float2* tab = (float2*)(ws + off);               off += (size_t)S_LEN * 80 * 8;

  // 1) convert to bf16 (Wq then Wkv contiguously -> fused B matrix)
  cvt_bf16_kernel<<<(int)(SH / 8 / 256), 256, 0, stream>>>(hs, Xb, (int)(SH / 8));
  cvt_bf16_kernel<<<HID * HID / 8 / 256, 256, 0, stream>>>(Wq, Wqkvb, HID * HID / 8);
  cvt_bf16_kernel<<<2 * HID * HID / 8 / 256, 256, 0, stream>>>(Wkv, Wqkvb + (size_t)HID * HID, 2 * HID * HID / 8);
  cvt_bf16_kernel<<<HID * HID / 8 / 256, 256, 0, stream>>>(Wd, Wdb, HID * HID / 8);

  // 2) RoPE table
  rope_table_kernel<<<64, 256, 0, stream>>>(tab);

  // 3) fused QKV projection: [2048,15360] = Xb @ [Wq|Wkv]^T
  gemm256<0><<<dim3(NQKV / 256, S_LEN / 256), 512, 0, stream>>>(
      Xb, Wqkvb, QKVraw, S_LEN, NQKV, HID, nullptr, nullptr);

  // 4) RoPE + relayout; V transpose (all reading fused QKVraw)
  rope_apply_kernel<<<S_LEN * NHEAD * 80 / 256, 256, 0, stream>>>(QKVraw, tab, Qr, HDIM, NQKV);
  rope_apply_kernel<<<S_LEN * NHEAD * 80 / 256, 256, 0, stream>>>(QKVraw + HID, tab, Kr, 2 * HDIM, NQKV);
  vtrans_kernel<<<dim3(S_LEN / 64, NHEAD), 256, 0, stream>>>(QKVraw + HID + HDIM, Vt, NQKV);

  // 5) attention (balanced pairing, raw barriers, 128 q-rows per block)
  attn_kernel<<<512, 512, 0, stream>>>(Qr, Kr, Vt, ctx);

  // 6) output projection + bias + residual (128² tile: 640 blocks fill the GPU)
  gemm_bt<1><<<dim3(HID / 128, S_LEN / 128), 256, 0, stream>>>(
      ctx, Wdb, out, S_LEN, HID, HID, bd, resid);
}